// Round 4
// baseline (638.238 us; speedup 1.0000x reference)
//
#include <hip/hip_runtime.h>
#include <cstdint>

// Problem constants (fixed by the reference): B=8, N=16384, D=64, P=100.
#define NB    8
#define NN    16384
#define ND    64
#define NP    100
#define ST    512          // sort threads per block
#define SE    32           // elements per sort thread (16384/512)

// ---------- sortable-key transforms ----------
__device__ __forceinline__ uint32_t f2s_u(uint32_t s) {
  // monotone map f32 bits -> u32: neg -> ~s, pos -> s | 0x80000000
  return s ^ (((uint32_t)((int32_t)s >> 31)) | 0x80000000u);
}
__device__ __forceinline__ float s2f(uint32_t u) {
  uint32_t m = (u & 0x80000000u) ? 0x80000000u : 0xFFFFFFFFu;
  return __uint_as_float(u ^ m);
}

// LDS bank swizzle on word index: spreads each thread's 32-word chunk across
// all 32 banks while preserving 16B (quad) contiguity for b128 ops.
__device__ __forceinline__ uint32_t swz(uint32_t w) {
  return w ^ ((w >> 3) & 0x1Cu);   // w ^ (((w>>5)&7)<<2)
}

// One LSD radix pass on 3-bit digit at shift sh (digits 0..7), stable,
// in-place in S[16384]. Keys arrive in k[] (if first) or are loaded from S.
__device__ __forceinline__ void radix_pass(uint32_t (&k)[SE], uint32_t* S,
                                           uint32_t* WG, int tid, int sh,
                                           bool first) {
  const int lane = tid & 63;
  const int wave = tid >> 6;
  const uint32_t t7 = (uint32_t)(tid & 7) << 2;

  if (!first) {
#pragma unroll
    for (int q = 0; q < 8; q++) {
      uint4 v = *(const uint4*)(S + (tid << 5) + (((uint32_t)(q << 2)) ^ t7));
      k[4 * q + 0] = v.x; k[4 * q + 1] = v.y;
      k[4 * q + 2] = v.z; k[4 * q + 3] = v.w;
    }
  }

  // per-thread histogram: 8 bins x 8-bit bytes packed in one u64 (counts <= 32)
  uint64_t c = 0;
#pragma unroll
  for (int e = 0; e < SE; e++) {
    uint32_t d = (k[e] >> sh) & 7u;
    c += 1ull << (d << 3);
  }

  // unpack to 4 regs of u16-pairs: h[i] = bins (2i, 2i+1)
  uint32_t lo = (uint32_t)c, hi = (uint32_t)(c >> 32);
  uint32_t h[4], o[4];
  h[0] = (lo & 0xFFu) | ((lo & 0xFF00u) << 8);
  h[1] = ((lo >> 16) & 0xFFu) | ((lo >> 24) << 16);
  h[2] = (hi & 0xFFu) | ((hi & 0xFF00u) << 8);
  h[3] = ((hi >> 16) & 0xFFu) | ((hi >> 24) << 16);
#pragma unroll
  for (int i = 0; i < 4; i++) o[i] = h[i];

  // inclusive scan across 64 lanes (u16 SWAR)
#pragma unroll
  for (int off = 1; off <= 32; off <<= 1) {
#pragma unroll
    for (int i = 0; i < 4; i++) {
      uint32_t t = __shfl_up(h[i], (unsigned)off, 64);
      if (lane >= off) h[i] += t;
    }
  }

  if (lane == 63) {
#pragma unroll
    for (int i = 0; i < 4; i++) WG[(wave << 2) + i] = h[i];
  }
  __syncthreads();

  // wave 0, 32 lanes: G[w][bin] bases
  if (tid < 32) {
    uint32_t v = WG[tid];
    uint32_t own = v;
#pragma unroll
    for (int off = 4; off <= 16; off <<= 1) {
      uint32_t t = __shfl_up(v, (unsigned)off, 64);
      if (tid >= off) v += t;
    }
    uint32_t wexcl = v - own;
    uint32_t grand = __shfl(v, 28 + (tid & 3), 64);
    uint32_t gl = grand & 0xFFFFu, gh = grand >> 16;
    uint32_t ps = gl + gh, pincl = ps;
#pragma unroll
    for (int off = 1; off <= 2; off <<= 1) {
      uint32_t t = __shfl_up(pincl, (unsigned)off, 64);
      if ((tid & 3) >= off) pincl += t;
    }
    uint32_t pexcl = pincl - ps;
    uint32_t g0 = pexcl + (wexcl & 0xFFFFu);
    uint32_t g1 = pexcl + gl + (wexcl >> 16);
    WG[tid] = g0 | (g1 << 16);
  }
  __syncthreads();

  uint32_t p0 = WG[(wave << 2) + 0] + (h[0] - o[0]);
  uint32_t p1 = WG[(wave << 2) + 1] + (h[1] - o[1]);
  uint32_t p2 = WG[(wave << 2) + 2] + (h[2] - o[2]);
  uint32_t p3 = WG[(wave << 2) + 3] + (h[3] - o[3]);
  uint64_t pc0 = (uint64_t)p0 | ((uint64_t)p1 << 32);  // bins 0..3
  uint64_t pc1 = (uint64_t)p2 | ((uint64_t)p3 << 32);  // bins 4..7

#pragma unroll
  for (int e = 0; e < SE; e++) {
    uint32_t d = (k[e] >> sh) & 7u;
    uint32_t s16 = (d & 3u) << 4;
    bool lo4 = d < 4u;
    uint64_t t = lo4 ? pc0 : pc1;
    uint32_t pos = (uint32_t)(t >> s16) & 0xFFFFu;
    uint64_t inc = 1ull << s16;
    pc0 += lo4 ? inc : 0ull;
    pc1 += lo4 ? 0ull : inc;
    S[swz(pos)] = k[e];
  }
  __syncthreads();
}

// stable LSD radix over key bits [14..31] (6 passes x 3 bits)
__device__ __forceinline__ void radix18(uint32_t (&k)[SE], uint32_t* S,
                                        uint32_t* WG, int tid) {
  bool first = true;
  for (int sh = 14; sh < 32; sh += 3) {
    radix_pass(k, S, WG, tid, sh, first);
    first = false;
  }
}

// ---------- kernel 1: normalize theta rows ----------
__global__ void normalize_theta(const float* __restrict__ theta, float* __restrict__ tn) {
  const int p = blockIdx.x, t = threadIdx.x;
  float v = theta[p * ND + t];
  float ss = v * v;
#pragma unroll
  for (int off = 32; off >= 1; off >>= 1) ss += __shfl_xor(ss, off, 64);
  tn[p * ND + t] = v * rsqrtf(ss);
}

// ---------- kernel 2: project x OR y (blockIdx.y) onto all 100 directions ----
// theta staged in LDS (broadcast ds_read); 4 partial sums + p-unroll-2 for ILP.
__global__ __launch_bounds__(256, 4) void project_kernel(
    const float* __restrict__ x, const float* __restrict__ y,
    const float* __restrict__ tn, float* __restrict__ xp, float* __restrict__ yp) {
  __shared__ float TH[NP * ND];   // 25.6 KB
  const float* src = blockIdx.y ? y : x;
  float*       dst = blockIdx.y ? yp : xp;
  const int tid = threadIdx.x;
  const int t = blockIdx.x * 256 + tid;   // t = b*N + n
  const int b = t >> 14;
  const int n = t & (NN - 1);

  for (int i = tid; i < NP * ND / 4; i += 256)
    ((float4*)TH)[i] = ((const float4*)tn)[i];
  __syncthreads();

  float4 r[16];
  const float4* r4 = (const float4*)src + (long)t * 16;
#pragma unroll
  for (int q = 0; q < 16; q++) r[q] = r4[q];

  const long obase = ((long)b * NP) * NN + n;
  for (int p = 0; p < NP; p += 2) {
    const float4* thA = (const float4*)(TH + p * ND);
    const float4* thB = (const float4*)(TH + (p + 1) * ND);
    float pa[4] = {0.f, 0.f, 0.f, 0.f};
    float pb[4] = {0.f, 0.f, 0.f, 0.f};
#pragma unroll
    for (int q = 0; q < 16; q++) {
      float4 ta = thA[q], tb = thB[q];
      pa[q & 3] += r[q].x * ta.x + r[q].y * ta.y + r[q].z * ta.z + r[q].w * ta.w;
      pb[q & 3] += r[q].x * tb.x + r[q].y * tb.y + r[q].z * tb.z + r[q].w * tb.w;
    }
    dst[obase + (long)p * NN]       = (pa[0] + pa[1]) + (pa[2] + pa[3]);
    dst[obase + (long)(p + 1) * NN] = (pb[0] + pb[1]) + (pb[2] + pb[3]);
  }
}

// ---------- kernel 3: per-(b,p) radix-sort y, rank x, write diff ----------
__global__ __launch_bounds__(ST, 4) void sort_diff_kernel(
    const float* __restrict__ xp, float* __restrict__ yp) {
  __shared__ uint32_t S[NN];    // 64 KB
  __shared__ uint32_t WG[32];
  const int tid = threadIdx.x;
  const long sbase = (long)blockIdx.x * NN;
  const uint32_t t7 = (uint32_t)(tid & 7) << 2;
  uint32_t k[SE];

  // --- y keys: full value as sortable u32; radix on top 18 bits (stable) ---
  {
    const uint4* yg = (const uint4*)(yp + sbase) + (tid << 3);
#pragma unroll
    for (int q = 0; q < 8; q++) {
      uint4 v = yg[q];
      k[4 * q + 0] = f2s_u(v.x); k[4 * q + 1] = f2s_u(v.y);
      k[4 * q + 2] = f2s_u(v.z); k[4 * q + 3] = f2s_u(v.w);
    }
  }
  radix18(k, S, WG, tid);

  float ys[SE];
#pragma unroll
  for (int q = 0; q < 8; q++) {
    uint4 v = *(const uint4*)(S + (tid << 5) + (((uint32_t)(q << 2)) ^ t7));
    ys[4 * q + 0] = s2f(v.x); ys[4 * q + 1] = s2f(v.y);
    ys[4 * q + 2] = s2f(v.z); ys[4 * q + 3] = s2f(v.w);
  }

  // --- x keys: top-18-bit key | 14-bit original index ---
  {
    const uint4* xg = (const uint4*)(xp + sbase) + (tid << 3);
#pragma unroll
    for (int q = 0; q < 8; q++) {
      uint4 v = xg[q];
      uint32_t g = (uint32_t)(tid << 5) + (uint32_t)(4 * q);
      k[4 * q + 0] = (f2s_u(v.x) & 0xFFFFC000u) | (g + 0);
      k[4 * q + 1] = (f2s_u(v.y) & 0xFFFFC000u) | (g + 1);
      k[4 * q + 2] = (f2s_u(v.z) & 0xFFFFC000u) | (g + 2);
      k[4 * q + 3] = (f2s_u(v.w) & 0xFFFFC000u) | (g + 3);
    }
  }
  radix18(k, S, WG, tid);

  // --- rank -> orig index, then LDS permutation scatter ---
#pragma unroll
  for (int q = 0; q < 8; q++) {
    uint4 v = *(const uint4*)(S + (tid << 5) + (((uint32_t)(q << 2)) ^ t7));
    k[4 * q + 0] = v.x & 0x3FFFu; k[4 * q + 1] = v.y & 0x3FFFu;
    k[4 * q + 2] = v.z & 0x3FFFu; k[4 * q + 3] = v.w & 0x3FFFu;
  }
  __syncthreads();

#pragma unroll
  for (int e = 0; e < SE; e++) {
    S[swz(k[e])] = __float_as_uint(ys[e]);
  }
  __syncthreads();

  // --- linear, fully-coalesced epilogue: diff[n] = yscat[n] - x_proj[n] ---
  const uint4* xg = (const uint4*)(xp + sbase) + (tid << 3);
  float4* og = (float4*)(yp + sbase) + (tid << 3);
#pragma unroll
  for (int q = 0; q < 8; q++) {
    uint4 v = *(const uint4*)(S + (tid << 5) + (((uint32_t)(q << 2)) ^ t7));
    uint4 xb = xg[q];
    float4 o;
    o.x = __uint_as_float(v.x) - __uint_as_float(xb.x);
    o.y = __uint_as_float(v.y) - __uint_as_float(xb.y);
    o.z = __uint_as_float(v.z) - __uint_as_float(xb.z);
    o.w = __uint_as_float(v.w) - __uint_as_float(xb.w);
    og[q] = o;
  }
}

// ---------- kernel 4: out = x + (1/P) * sum_p diff[b,p,n] * theta_n[p,:] -----
// Each thread owns a 32-wide half of the D dimension (interleaved in the wave
// so dv loads coalesce); theta in LDS; p-unroll-2 keeps 2 loads in flight.
__global__ __launch_bounds__(256, 4) void combine_kernel(
    const float* __restrict__ x, const float* __restrict__ diff,
    const float* __restrict__ tn, float* __restrict__ out) {
  __shared__ float TH[NP * ND];   // 25.6 KB
  const int tid = threadIdx.x;
  for (int i = tid; i < NP * ND / 4; i += 256)
    ((float4*)TH)[i] = ((const float4*)tn)[i];
  __syncthreads();

  const int t2 = blockIdx.x * 256 + tid;   // 2 threads per (b,n)
  const int h  = t2 & 1;                   // d-half
  const int t  = t2 >> 1;                  // b*N + n
  const int b  = t >> 14;
  const int n  = t & (NN - 1);

  float4 acc[8];
#pragma unroll
  for (int q = 0; q < 8; q++) acc[q] = make_float4(0.f, 0.f, 0.f, 0.f);

  const long dbase = ((long)b * NP) * NN + n;
  const float* thh = TH + h * 32;
  for (int p = 0; p < NP; p += 2) {
    const float dv0 = diff[dbase + (long)p * NN];
    const float dv1 = diff[dbase + (long)(p + 1) * NN];
    const float4* t0 = (const float4*)(thh + p * ND);
    const float4* t1 = (const float4*)(thh + (p + 1) * ND);
#pragma unroll
    for (int q = 0; q < 8; q++) {
      float4 a = t0[q], c = t1[q];
      acc[q].x += dv0 * a.x + dv1 * c.x;
      acc[q].y += dv0 * a.y + dv1 * c.y;
      acc[q].z += dv0 * a.z + dv1 * c.z;
      acc[q].w += dv0 * a.w + dv1 * c.w;
    }
  }

  const float4* xr4 = (const float4*)x + (long)t * 16 + h * 8;
  float4* o4 = (float4*)out + (long)t * 16 + h * 8;
  const float inv = 1.0f / (float)NP;
#pragma unroll
  for (int q = 0; q < 8; q++) {
    float4 xv = xr4[q];
    float4 o;
    o.x = xv.x + acc[q].x * inv;
    o.y = xv.y + acc[q].y * inv;
    o.z = xv.z + acc[q].z * inv;
    o.w = xv.w + acc[q].w * inv;
    o4[q] = o;
  }
}

extern "C" void kernel_launch(void* const* d_in, const int* in_sizes, int n_in,
                              void* d_out, int out_size, void* d_ws, size_t ws_size,
                              hipStream_t stream) {
  const float* x     = (const float*)d_in[0];
  const float* y     = (const float*)d_in[1];
  const float* theta = (const float*)d_in[2];
  float* out = (float*)d_out;

  // workspace layout: [theta_n: 32KB pad][x_proj: 52.4MB][y_proj/diff: 52.4MB]
  float* tn = (float*)d_ws;
  float* xp = (float*)((char*)d_ws + (1 << 15));
  float* yp = xp + (size_t)NB * NP * NN;

  normalize_theta<<<dim3(NP), dim3(ND), 0, stream>>>(theta, tn);
  project_kernel<<<dim3((NB * NN) / 256, 2), dim3(256), 0, stream>>>(x, y, tn, xp, yp);
  sort_diff_kernel<<<dim3(NB * NP), dim3(ST), 0, stream>>>(xp, yp);
  combine_kernel<<<dim3((NB * NN * 2) / 256), dim3(256), 0, stream>>>(x, yp, tn, out);
}

// Round 5
// 518.087 us; speedup vs baseline: 1.2319x; 1.2319x over previous
//
#include <hip/hip_runtime.h>
#include <cstdint>

// Problem constants (fixed by the reference): B=8, N=16384, D=64, P=100.
#define NB    8
#define NN    16384
#define ND    64
#define NP    100
#define ST    512          // sort threads per block
#define SE    32           // elements per sort thread (16384/512)

// ---------- sortable-key transforms ----------
__device__ __forceinline__ uint32_t f2s_u(uint32_t s) {
  return s ^ (((uint32_t)((int32_t)s >> 31)) | 0x80000000u);
}
__device__ __forceinline__ float s2f(uint32_t u) {
  uint32_t m = (u & 0x80000000u) ? 0x80000000u : 0xFFFFFFFFu;
  return __uint_as_float(u ^ m);
}

// LDS bank swizzle on word index (16B-contiguity-preserving)
__device__ __forceinline__ uint32_t swz(uint32_t w) {
  return w ^ ((w >> 3) & 0x1Cu);
}

// One LSD radix pass on 3-bit digit at shift sh, stable, in-place in S[16384].
__device__ __forceinline__ void radix_pass(uint32_t (&k)[SE], uint32_t* S,
                                           uint32_t* WG, int tid, int sh,
                                           bool first) {
  const int lane = tid & 63;
  const int wave = tid >> 6;
  const uint32_t t7 = (uint32_t)(tid & 7) << 2;

  if (!first) {
#pragma unroll
    for (int q = 0; q < 8; q++) {
      uint4 v = *(const uint4*)(S + (tid << 5) + (((uint32_t)(q << 2)) ^ t7));
      k[4 * q + 0] = v.x; k[4 * q + 1] = v.y;
      k[4 * q + 2] = v.z; k[4 * q + 3] = v.w;
    }
  }

  uint64_t c = 0;
#pragma unroll
  for (int e = 0; e < SE; e++) {
    uint32_t d = (k[e] >> sh) & 7u;
    c += 1ull << (d << 3);
  }

  uint32_t lo = (uint32_t)c, hi = (uint32_t)(c >> 32);
  uint32_t h[4], o[4];
  h[0] = (lo & 0xFFu) | ((lo & 0xFF00u) << 8);
  h[1] = ((lo >> 16) & 0xFFu) | ((lo >> 24) << 16);
  h[2] = (hi & 0xFFu) | ((hi & 0xFF00u) << 8);
  h[3] = ((hi >> 16) & 0xFFu) | ((hi >> 24) << 16);
#pragma unroll
  for (int i = 0; i < 4; i++) o[i] = h[i];

#pragma unroll
  for (int off = 1; off <= 32; off <<= 1) {
#pragma unroll
    for (int i = 0; i < 4; i++) {
      uint32_t t = __shfl_up(h[i], (unsigned)off, 64);
      if (lane >= off) h[i] += t;
    }
  }

  if (lane == 63) {
#pragma unroll
    for (int i = 0; i < 4; i++) WG[(wave << 2) + i] = h[i];
  }
  __syncthreads();

  if (tid < 32) {
    uint32_t v = WG[tid];
    uint32_t own = v;
#pragma unroll
    for (int off = 4; off <= 16; off <<= 1) {
      uint32_t t = __shfl_up(v, (unsigned)off, 64);
      if (tid >= off) v += t;
    }
    uint32_t wexcl = v - own;
    uint32_t grand = __shfl(v, 28 + (tid & 3), 64);
    uint32_t gl = grand & 0xFFFFu, gh = grand >> 16;
    uint32_t ps = gl + gh, pincl = ps;
#pragma unroll
    for (int off = 1; off <= 2; off <<= 1) {
      uint32_t t = __shfl_up(pincl, (unsigned)off, 64);
      if ((tid & 3) >= off) pincl += t;
    }
    uint32_t pexcl = pincl - ps;
    uint32_t g0 = pexcl + (wexcl & 0xFFFFu);
    uint32_t g1 = pexcl + gl + (wexcl >> 16);
    WG[tid] = g0 | (g1 << 16);
  }
  __syncthreads();

  uint32_t p0 = WG[(wave << 2) + 0] + (h[0] - o[0]);
  uint32_t p1 = WG[(wave << 2) + 1] + (h[1] - o[1]);
  uint32_t p2 = WG[(wave << 2) + 2] + (h[2] - o[2]);
  uint32_t p3 = WG[(wave << 2) + 3] + (h[3] - o[3]);
  uint64_t pc0 = (uint64_t)p0 | ((uint64_t)p1 << 32);
  uint64_t pc1 = (uint64_t)p2 | ((uint64_t)p3 << 32);

#pragma unroll
  for (int e = 0; e < SE; e++) {
    uint32_t d = (k[e] >> sh) & 7u;
    uint32_t s16 = (d & 3u) << 4;
    bool lo4 = d < 4u;
    uint64_t t = lo4 ? pc0 : pc1;
    uint32_t pos = (uint32_t)(t >> s16) & 0xFFFFu;
    uint64_t inc = 1ull << s16;
    pc0 += lo4 ? inc : 0ull;
    pc1 += lo4 ? 0ull : inc;
    S[swz(pos)] = k[e];
  }
  __syncthreads();
}

__device__ __forceinline__ void radix18(uint32_t (&k)[SE], uint32_t* S,
                                        uint32_t* WG, int tid) {
  bool first = true;
  for (int sh = 14; sh < 32; sh += 3) {
    radix_pass(k, S, WG, tid, sh, first);
    first = false;
  }
}

// ---------- kernel 1: normalize theta rows ----------
__global__ void normalize_theta(const float* __restrict__ theta, float* __restrict__ tn) {
  const int p = blockIdx.x, t = threadIdx.x;
  float v = theta[p * ND + t];
  float ss = v * v;
#pragma unroll
  for (int off = 32; off >= 1; off >>= 1) ss += __shfl_xor(ss, off, 64);
  tn[p * ND + t] = v * rsqrtf(ss);
}

// ---------- kernel 2: transposed projection ----------
// lane <-> projection p (theta row pinned in 16 VGPR quads); row data arrives
// as wave-uniform scalars (readfirstlane base -> s_load), so the inner loop is
// v_fma(v_theta, s_x). Wave tile: 64 p x 16 rows; block: 128 p x 32 rows.
// Output transposed through LDS (stride 33 -> 2-way bank = free) for
// contiguous 128B global stores.
__global__ __launch_bounds__(256) void project_t(
    const float* __restrict__ x, const float* __restrict__ y,
    const float* __restrict__ tn, float* __restrict__ xp, float* __restrict__ yp) {
  __shared__ float T[128 * 33];   // 16.9 KB
  const int tid  = threadIdx.x;
  const int lane = tid & 63;
  const int wave = tid >> 6;
  const int phalf = wave & 1;          // p in [0,64) or [64,128)
  const int rg    = wave >> 1;         // row-group 0/1 (16 rows each)
  const int p     = phalf * 64 + lane;

  const int blk    = blockIdx.x;       // 8192 blocks
  const int is_y   = blk & 1;
  const int rowblk = blk >> 1;         // 0..4095, 32 rows each
  const float* src = is_y ? y : x;
  float*       dst = is_y ? yp : xp;

  // theta row for my p, pinned in registers (zeros for pad lanes)
  float4 th[16];
  if (p < NP) {
    const float4* tp = (const float4*)(tn + p * ND);
#pragma unroll
    for (int q = 0; q < 16; q++) th[q] = tp[q];
  } else {
#pragma unroll
    for (int q = 0; q < 16; q++) th[q] = make_float4(0.f, 0.f, 0.f, 0.f);
  }

  // wave-uniform row base (global row index into [0, B*N))
  const int row0 = __builtin_amdgcn_readfirstlane(rowblk * 32 + rg * 16);
  const float* rb = src + (long)row0 * ND;

  float acc[16];
#pragma unroll
  for (int r = 0; r < 16; r++) acc[r] = 0.f;

#pragma unroll
  for (int r = 0; r < 16; r++) {
    const float4* rowp = (const float4*)(rb + r * ND);
#pragma unroll
    for (int q = 0; q < 16; q++) {
      const float4 sx = rowp[q];   // wave-uniform -> s_load
      acc[r] += th[q].x * sx.x + th[q].y * sx.y + th[q].z * sx.z + th[q].w * sx.w;
    }
  }

  // stage [p][r] tile in LDS (stride 33: 2-way bank aliasing = free)
#pragma unroll
  for (int r = 0; r < 16; r++) T[p * 33 + rg * 16 + r] = acc[r];
  __syncthreads();

  // store: thread g -> p' = g>>1, row-half = (g&1)*16; 64B contiguous per thread
  const int sp = tid >> 1;
  const int sh = (tid & 1) * 16;
  if (sp < NP) {
    const int rowbase = (blk >> 1) * 32;           // block's first global row
    const int b  = rowbase >> 14;
    const int n0 = rowbase & (NN - 1);
    float* op = dst + ((long)b * NP + sp) * NN + n0 + sh;
#pragma unroll
    for (int q = 0; q < 4; q++) {
      float4 v;
      v.x = T[sp * 33 + sh + 4 * q + 0];
      v.y = T[sp * 33 + sh + 4 * q + 1];
      v.z = T[sp * 33 + sh + 4 * q + 2];
      v.w = T[sp * 33 + sh + 4 * q + 3];
      *(float4*)(op + 4 * q) = v;
    }
  }
}

// ---------- kernel 3: per-(b,p) radix-sort y, rank x, write diff ----------
__global__ __launch_bounds__(ST, 4) void sort_diff_kernel(
    const float* __restrict__ xp, float* __restrict__ yp) {
  __shared__ uint32_t S[NN];    // 64 KB
  __shared__ uint32_t WG[32];
  const int tid = threadIdx.x;
  const long sbase = (long)blockIdx.x * NN;
  const uint32_t t7 = (uint32_t)(tid & 7) << 2;
  uint32_t k[SE];

  // --- y keys: full value as sortable u32 ---
  {
    const uint4* yg = (const uint4*)(yp + sbase) + (tid << 3);
#pragma unroll
    for (int q = 0; q < 8; q++) {
      uint4 v = yg[q];
      k[4 * q + 0] = f2s_u(v.x); k[4 * q + 1] = f2s_u(v.y);
      k[4 * q + 2] = f2s_u(v.z); k[4 * q + 3] = f2s_u(v.w);
    }
  }
  radix18(k, S, WG, tid);

  float ys[SE];
#pragma unroll
  for (int q = 0; q < 8; q++) {
    uint4 v = *(const uint4*)(S + (tid << 5) + (((uint32_t)(q << 2)) ^ t7));
    ys[4 * q + 0] = s2f(v.x); ys[4 * q + 1] = s2f(v.y);
    ys[4 * q + 2] = s2f(v.z); ys[4 * q + 3] = s2f(v.w);
  }

  // --- x keys: top-18-bit key | 14-bit original index ---
  {
    const uint4* xg = (const uint4*)(xp + sbase) + (tid << 3);
#pragma unroll
    for (int q = 0; q < 8; q++) {
      uint4 v = xg[q];
      uint32_t g = (uint32_t)(tid << 5) + (uint32_t)(4 * q);
      k[4 * q + 0] = (f2s_u(v.x) & 0xFFFFC000u) | (g + 0);
      k[4 * q + 1] = (f2s_u(v.y) & 0xFFFFC000u) | (g + 1);
      k[4 * q + 2] = (f2s_u(v.z) & 0xFFFFC000u) | (g + 2);
      k[4 * q + 3] = (f2s_u(v.w) & 0xFFFFC000u) | (g + 3);
    }
  }
  radix18(k, S, WG, tid);

  // --- rank -> orig index, then LDS permutation scatter ---
#pragma unroll
  for (int q = 0; q < 8; q++) {
    uint4 v = *(const uint4*)(S + (tid << 5) + (((uint32_t)(q << 2)) ^ t7));
    k[4 * q + 0] = v.x & 0x3FFFu; k[4 * q + 1] = v.y & 0x3FFFu;
    k[4 * q + 2] = v.z & 0x3FFFu; k[4 * q + 3] = v.w & 0x3FFFu;
  }
  __syncthreads();

#pragma unroll
  for (int e = 0; e < SE; e++) {
    S[swz(k[e])] = __float_as_uint(ys[e]);
  }
  __syncthreads();

  // --- linear, coalesced epilogue: diff[n] = yscat[n] - x_proj[n] ---
  const uint4* xg = (const uint4*)(xp + sbase) + (tid << 3);
  float4* og = (float4*)(yp + sbase) + (tid << 3);
#pragma unroll
  for (int q = 0; q < 8; q++) {
    uint4 v = *(const uint4*)(S + (tid << 5) + (((uint32_t)(q << 2)) ^ t7));
    uint4 xb = xg[q];
    float4 o;
    o.x = __uint_as_float(v.x) - __uint_as_float(xb.x);
    o.y = __uint_as_float(v.y) - __uint_as_float(xb.y);
    o.z = __uint_as_float(v.z) - __uint_as_float(xb.z);
    o.w = __uint_as_float(v.w) - __uint_as_float(xb.w);
    og[q] = o;
  }
}

// ---------- kernel 4: transposed combine ----------
// lane <-> d (D=64 exact); diff values wave-uniform -> s_load_dwordx16 (one
// 64B line per (p, 16-row tile)); theta column via coalesced vector load.
// No LDS; stores are full 256B rows.
__global__ __launch_bounds__(256) void combine_t(
    const float* __restrict__ x, const float* __restrict__ diff,
    const float* __restrict__ tn, float* __restrict__ out) {
  const int tid  = threadIdx.x;
  const int lane = tid & 63;
  const int wave = tid >> 6;

  const int row0 = __builtin_amdgcn_readfirstlane(blockIdx.x * 64 + wave * 16);
  const int b  = row0 >> 14;
  const int n0 = row0 & (NN - 1);
  const float* dbase = diff + ((long)b * NP) * NN + n0;

  float acc[16];
#pragma unroll
  for (int r = 0; r < 16; r++) acc[r] = 0.f;

#pragma unroll 4
  for (int p = 0; p < NP; p++) {
    const float th = tn[p * ND + lane];          // coalesced vector load
    const float* dp = dbase + (long)p * NN;      // wave-uniform
#pragma unroll
    for (int r = 0; r < 16; r++) {
      acc[r] += dp[r] * th;                      // s_load operand
    }
  }

  const float inv = 1.0f / (float)NP;
#pragma unroll
  for (int r = 0; r < 16; r++) {
    const long off = (long)(row0 + r) * ND + lane;
    out[off] = x[off] + acc[r] * inv;
  }
}

extern "C" void kernel_launch(void* const* d_in, const int* in_sizes, int n_in,
                              void* d_out, int out_size, void* d_ws, size_t ws_size,
                              hipStream_t stream) {
  const float* x     = (const float*)d_in[0];
  const float* y     = (const float*)d_in[1];
  const float* theta = (const float*)d_in[2];
  float* out = (float*)d_out;

  // workspace layout: [theta_n: 32KB pad][x_proj: 52.4MB][y_proj/diff: 52.4MB]
  float* tn = (float*)d_ws;
  float* xp = (float*)((char*)d_ws + (1 << 15));
  float* yp = xp + (size_t)NB * NP * NN;

  normalize_theta<<<dim3(NP), dim3(ND), 0, stream>>>(theta, tn);
  project_t<<<dim3(2 * (NB * NN) / 32), dim3(256), 0, stream>>>(x, y, tn, xp, yp);
  sort_diff_kernel<<<dim3(NB * NP), dim3(ST), 0, stream>>>(xp, yp);
  combine_t<<<dim3((NB * NN) / 64), dim3(256), 0, stream>>>(x, yp, tn, out);
}

// Round 6
// 366.291 us; speedup vs baseline: 1.7424x; 1.4144x over previous
//
#include <hip/hip_runtime.h>
#include <cstdint>

// Problem constants (fixed by the reference): B=8, N=16384, D=64, P=100.
#define NB    8
#define NN    16384
#define ND    64
#define NP    100
#define NPP   128          // theta rows padded (zeros) for MFMA K/N tiling
#define ST    512          // sort threads per block
#define SE    32           // elements per sort thread (16384/512)

typedef __attribute__((ext_vector_type(8))) short short8;   // 8 bf16 (4 VGPRs)
typedef __attribute__((ext_vector_type(4))) float f32x4;    // MFMA C/D

// ---------- bf16 convert (RNE) ----------
__device__ __forceinline__ short bf16c(float f) {
  uint32_t u = __float_as_uint(f);
  u = u + 0x7FFFu + ((u >> 16) & 1u);
  return (short)(u >> 16);
}

// ---------- sortable-key transforms ----------
__device__ __forceinline__ uint32_t f2s_u(uint32_t s) {
  return s ^ (((uint32_t)((int32_t)s >> 31)) | 0x80000000u);
}
__device__ __forceinline__ float s2f(uint32_t u) {
  uint32_t m = (u & 0x80000000u) ? 0x80000000u : 0xFFFFFFFFu;
  return __uint_as_float(u ^ m);
}

// LDS bank swizzle on word index (16B-contiguity-preserving)
__device__ __forceinline__ uint32_t swz(uint32_t w) {
  return w ^ ((w >> 3) & 0x1Cu);
}

// One LSD radix pass on 3-bit digit at shift sh, stable, in-place in S[16384].
__device__ __forceinline__ void radix_pass(uint32_t (&k)[SE], uint32_t* S,
                                           uint32_t* WG, int tid, int sh,
                                           bool first) {
  const int lane = tid & 63;
  const int wave = tid >> 6;
  const uint32_t t7 = (uint32_t)(tid & 7) << 2;

  if (!first) {
#pragma unroll
    for (int q = 0; q < 8; q++) {
      uint4 v = *(const uint4*)(S + (tid << 5) + (((uint32_t)(q << 2)) ^ t7));
      k[4 * q + 0] = v.x; k[4 * q + 1] = v.y;
      k[4 * q + 2] = v.z; k[4 * q + 3] = v.w;
    }
  }

  uint64_t c = 0;
#pragma unroll
  for (int e = 0; e < SE; e++) {
    uint32_t d = (k[e] >> sh) & 7u;
    c += 1ull << (d << 3);
  }

  uint32_t lo = (uint32_t)c, hi = (uint32_t)(c >> 32);
  uint32_t h[4], o[4];
  h[0] = (lo & 0xFFu) | ((lo & 0xFF00u) << 8);
  h[1] = ((lo >> 16) & 0xFFu) | ((lo >> 24) << 16);
  h[2] = (hi & 0xFFu) | ((hi & 0xFF00u) << 8);
  h[3] = ((hi >> 16) & 0xFFu) | ((hi >> 24) << 16);
#pragma unroll
  for (int i = 0; i < 4; i++) o[i] = h[i];

#pragma unroll
  for (int off = 1; off <= 32; off <<= 1) {
#pragma unroll
    for (int i = 0; i < 4; i++) {
      uint32_t t = __shfl_up(h[i], (unsigned)off, 64);
      if (lane >= off) h[i] += t;
    }
  }

  if (lane == 63) {
#pragma unroll
    for (int i = 0; i < 4; i++) WG[(wave << 2) + i] = h[i];
  }
  __syncthreads();

  if (tid < 32) {
    uint32_t v = WG[tid];
    uint32_t own = v;
#pragma unroll
    for (int off = 4; off <= 16; off <<= 1) {
      uint32_t t = __shfl_up(v, (unsigned)off, 64);
      if (tid >= off) v += t;
    }
    uint32_t wexcl = v - own;
    uint32_t grand = __shfl(v, 28 + (tid & 3), 64);
    uint32_t gl = grand & 0xFFFFu, gh = grand >> 16;
    uint32_t ps = gl + gh, pincl = ps;
#pragma unroll
    for (int off = 1; off <= 2; off <<= 1) {
      uint32_t t = __shfl_up(pincl, (unsigned)off, 64);
      if ((tid & 3) >= off) pincl += t;
    }
    uint32_t pexcl = pincl - ps;
    uint32_t g0 = pexcl + (wexcl & 0xFFFFu);
    uint32_t g1 = pexcl + gl + (wexcl >> 16);
    WG[tid] = g0 | (g1 << 16);
  }
  __syncthreads();

  uint32_t p0 = WG[(wave << 2) + 0] + (h[0] - o[0]);
  uint32_t p1 = WG[(wave << 2) + 1] + (h[1] - o[1]);
  uint32_t p2 = WG[(wave << 2) + 2] + (h[2] - o[2]);
  uint32_t p3 = WG[(wave << 2) + 3] + (h[3] - o[3]);
  uint64_t pc0 = (uint64_t)p0 | ((uint64_t)p1 << 32);
  uint64_t pc1 = (uint64_t)p2 | ((uint64_t)p3 << 32);

#pragma unroll
  for (int e = 0; e < SE; e++) {
    uint32_t d = (k[e] >> sh) & 7u;
    uint32_t s16 = (d & 3u) << 4;
    bool lo4 = d < 4u;
    uint64_t t = lo4 ? pc0 : pc1;
    uint32_t pos = (uint32_t)(t >> s16) & 0xFFFFu;
    uint64_t inc = 1ull << s16;
    pc0 += lo4 ? inc : 0ull;
    pc1 += lo4 ? 0ull : inc;
    S[swz(pos)] = k[e];
  }
  __syncthreads();
}

__device__ __forceinline__ void radix18(uint32_t (&k)[SE], uint32_t* S,
                                        uint32_t* WG, int tid) {
  bool first = true;
  for (int sh = 14; sh < 32; sh += 3) {
    radix_pass(k, S, WG, tid, sh, first);
    first = false;
  }
}

// ---------- kernel 1: normalize theta rows -> bf16, zero-padded to 128 ------
__global__ void normalize_theta(const float* __restrict__ theta,
                                ushort* __restrict__ thb) {
  const int p = blockIdx.x, t = threadIdx.x;
  if (p < NP) {
    float v = theta[p * ND + t];
    float ss = v * v;
#pragma unroll
    for (int off = 32; off >= 1; off >>= 1) ss += __shfl_xor(ss, off, 64);
    thb[p * ND + t] = (ushort)bf16c(v * rsqrtf(ss));
  } else {
    thb[p * ND + t] = 0;
  }
}

// ---------- kernel 2: MFMA projection ----------
// C[m=bn][n=p] = sum_k srcrow[m][k]*theta[p][k].  One wave = 16-row M-tile x
// 7 p-tiles of 16, K=64 = 2 chained mfma_f32_16x16x32_bf16.
// A[m=lane&15][k=quad*8+j]; B[k=quad*8+j][n=lane&15]; C col=lane&15,
// row=quad*4+reg -> stores are contiguous float4 in the [p][n] output layout.
__global__ __launch_bounds__(256) void project_mfma(
    const float* __restrict__ x, const float* __restrict__ y,
    const ushort* __restrict__ thb, float* __restrict__ xp,
    float* __restrict__ yp) {
  const int tid  = threadIdx.x;
  const int lane = tid & 63;
  const int quad = lane >> 4;
  const int mloc = lane & 15;
  const int wave = tid >> 6;

  const int blk    = blockIdx.x;        // 4096 blocks
  const int is_y   = blk & 1;
  const int rowblk = blk >> 1;          // 64 rows per rowblk
  const float* src = is_y ? y : x;
  float*       dst = is_y ? yp : xp;

  const int m0 = rowblk * 64 + wave * 16;       // wave's first global row
  const int b  = m0 >> 14;
  const int n0 = m0 & (NN - 1);

  // A fragments: row m0+mloc, cols [quad*8, +8) and [32+quad*8, +8)
  const float* ap = src + (long)(m0 + mloc) * ND + quad * 8;
  float4 q0 = *(const float4*)(ap + 0);
  float4 q1 = *(const float4*)(ap + 4);
  float4 q2 = *(const float4*)(ap + 32);
  float4 q3 = *(const float4*)(ap + 36);
  short8 a0, a1;
  a0[0] = bf16c(q0.x); a0[1] = bf16c(q0.y); a0[2] = bf16c(q0.z); a0[3] = bf16c(q0.w);
  a0[4] = bf16c(q1.x); a0[5] = bf16c(q1.y); a0[6] = bf16c(q1.z); a0[7] = bf16c(q1.w);
  a1[0] = bf16c(q2.x); a1[1] = bf16c(q2.y); a1[2] = bf16c(q2.z); a1[3] = bf16c(q2.w);
  a1[4] = bf16c(q3.x); a1[5] = bf16c(q3.y); a1[6] = bf16c(q3.z); a1[7] = bf16c(q3.w);

  const f32x4 zero = {0.f, 0.f, 0.f, 0.f};
#pragma unroll
  for (int t = 0; t < 7; t++) {
    const int p = t * 16 + mloc;
    // B frags: theta row p, cols quad*8.. and 32+quad*8.. (16B contiguous)
    const short8 b0 = *(const short8*)(thb + p * ND + quad * 8);
    const short8 b1 = *(const short8*)(thb + p * ND + 32 + quad * 8);
    f32x4 acc = __builtin_amdgcn_mfma_f32_16x16x32_bf16(a0, b0, zero, 0, 0, 0);
    acc = __builtin_amdgcn_mfma_f32_16x16x32_bf16(a1, b1, acc, 0, 0, 0);
    if (t < 6 || mloc < (NP - 96)) {
      float* op = dst + ((long)b * NP + p) * NN + n0 + quad * 4;
      *(f32x4*)op = acc;   // rows quad*4+r are consecutive n -> float4
    }
  }
}

// ---------- kernel 3: per-(b,p) radix-sort y, rank x, write diff ----------
__global__ __launch_bounds__(ST, 4) void sort_diff_kernel(
    const float* __restrict__ xp, float* __restrict__ yp) {
  __shared__ uint32_t S[NN];    // 64 KB
  __shared__ uint32_t WG[32];
  const int tid = threadIdx.x;
  const long sbase = (long)blockIdx.x * NN;
  const uint32_t t7 = (uint32_t)(tid & 7) << 2;
  uint32_t k[SE];

  {
    const uint4* yg = (const uint4*)(yp + sbase) + (tid << 3);
#pragma unroll
    for (int q = 0; q < 8; q++) {
      uint4 v = yg[q];
      k[4 * q + 0] = f2s_u(v.x); k[4 * q + 1] = f2s_u(v.y);
      k[4 * q + 2] = f2s_u(v.z); k[4 * q + 3] = f2s_u(v.w);
    }
  }
  radix18(k, S, WG, tid);

  float ys[SE];
#pragma unroll
  for (int q = 0; q < 8; q++) {
    uint4 v = *(const uint4*)(S + (tid << 5) + (((uint32_t)(q << 2)) ^ t7));
    ys[4 * q + 0] = s2f(v.x); ys[4 * q + 1] = s2f(v.y);
    ys[4 * q + 2] = s2f(v.z); ys[4 * q + 3] = s2f(v.w);
  }

  {
    const uint4* xg = (const uint4*)(xp + sbase) + (tid << 3);
#pragma unroll
    for (int q = 0; q < 8; q++) {
      uint4 v = xg[q];
      uint32_t g = (uint32_t)(tid << 5) + (uint32_t)(4 * q);
      k[4 * q + 0] = (f2s_u(v.x) & 0xFFFFC000u) | (g + 0);
      k[4 * q + 1] = (f2s_u(v.y) & 0xFFFFC000u) | (g + 1);
      k[4 * q + 2] = (f2s_u(v.z) & 0xFFFFC000u) | (g + 2);
      k[4 * q + 3] = (f2s_u(v.w) & 0xFFFFC000u) | (g + 3);
    }
  }
  radix18(k, S, WG, tid);

#pragma unroll
  for (int q = 0; q < 8; q++) {
    uint4 v = *(const uint4*)(S + (tid << 5) + (((uint32_t)(q << 2)) ^ t7));
    k[4 * q + 0] = v.x & 0x3FFFu; k[4 * q + 1] = v.y & 0x3FFFu;
    k[4 * q + 2] = v.z & 0x3FFFu; k[4 * q + 3] = v.w & 0x3FFFu;
  }
  __syncthreads();

#pragma unroll
  for (int e = 0; e < SE; e++) {
    S[swz(k[e])] = __float_as_uint(ys[e]);
  }
  __syncthreads();

  const uint4* xg = (const uint4*)(xp + sbase) + (tid << 3);
  float4* og = (float4*)(yp + sbase) + (tid << 3);
#pragma unroll
  for (int q = 0; q < 8; q++) {
    uint4 v = *(const uint4*)(S + (tid << 5) + (((uint32_t)(q << 2)) ^ t7));
    uint4 xb = xg[q];
    float4 o;
    o.x = __uint_as_float(v.x) - __uint_as_float(xb.x);
    o.y = __uint_as_float(v.y) - __uint_as_float(xb.y);
    o.z = __uint_as_float(v.z) - __uint_as_float(xb.z);
    o.w = __uint_as_float(v.w) - __uint_as_float(xb.w);
    og[q] = o;
  }
}

// ---------- kernel 4: MFMA combine ----------
// out[bn][d] = x[bn][d] + (1/P) * sum_p diff[b][p][n] * theta[p][d].
// A[m=bn][k=p] gathered from the [b][p][n] diff layout (64B line per
// (quad,j)); K padded 100->128 with zero A (and theta rows 100..127 = 0).
__global__ __launch_bounds__(256) void combine_mfma(
    const float* __restrict__ x, const float* __restrict__ diff,
    const ushort* __restrict__ thb, float* __restrict__ out) {
  const int tid  = threadIdx.x;
  const int lane = tid & 63;
  const int quad = lane >> 4;
  const int mloc = lane & 15;
  const int wave = tid >> 6;

  const int m0 = blockIdx.x * 64 + wave * 16;   // wave's first global row
  const int b  = m0 >> 14;
  const int n0 = m0 & (NN - 1);

  // A fragments: diff[b][k][n0+mloc], k = kf*32 + quad*8 + j (0 for k>=NP)
  const float* dbase = diff + ((long)b * NP) * NN + n0 + mloc;
  short8 a[4];
#pragma unroll
  for (int kf = 0; kf < 4; kf++) {
#pragma unroll
    for (int j = 0; j < 8; j++) {
      const int p = kf * 32 + quad * 8 + j;
      const float v = (p < NP) ? dbase[(long)p * NN] : 0.0f;
      a[kf][j] = bf16c(v);
    }
  }

  const float inv = 1.0f / (float)NP;
  const f32x4 zero = {0.f, 0.f, 0.f, 0.f};
#pragma unroll
  for (int t = 0; t < 4; t++) {
    const int d = t * 16 + mloc;
    f32x4 acc = zero;
#pragma unroll
    for (int kf = 0; kf < 4; kf++) {
      short8 bf;
#pragma unroll
      for (int j = 0; j < 8; j++) {
        const int p = kf * 32 + quad * 8 + j;
        bf[j] = (short)thb[p * ND + d];
      }
      acc = __builtin_amdgcn_mfma_f32_16x16x32_bf16(a[kf], bf, acc, 0, 0, 0);
    }
#pragma unroll
    for (int r = 0; r < 4; r++) {
      const long off = (long)(m0 + quad * 4 + r) * ND + d;
      out[off] = x[off] + acc[r] * inv;
    }
  }
}

extern "C" void kernel_launch(void* const* d_in, const int* in_sizes, int n_in,
                              void* d_out, int out_size, void* d_ws, size_t ws_size,
                              hipStream_t stream) {
  const float* x     = (const float*)d_in[0];
  const float* y     = (const float*)d_in[1];
  const float* theta = (const float*)d_in[2];
  float* out = (float*)d_out;

  // workspace: [thb bf16 128x64: 16KB, pad 32KB][xp 52.4MB][yp/diff 52.4MB]
  ushort* thb = (ushort*)d_ws;
  float* xp = (float*)((char*)d_ws + (1 << 15));
  float* yp = xp + (size_t)NB * NP * NN;

  normalize_theta<<<dim3(NPP), dim3(ND), 0, stream>>>(theta, thb);
  project_mfma<<<dim3(2 * (NB * NN) / 64), dim3(256), 0, stream>>>(x, y, thb, xp, yp);
  sort_diff_kernel<<<dim3(NB * NP), dim3(ST), 0, stream>>>(xp, yp);
  combine_mfma<<<dim3((NB * NN) / 64), dim3(256), 0, stream>>>(x, yp, thb, out);
}